// Round 4
// baseline (44.011 us; speedup 1.0000x reference)
//
#include <hip/hip_runtime.h>

// Problem constants (from reference setup_inputs)
#define N_  8
#define K_  32
#define TK_ 128
#define TC_ 256
#define D_  512
#define D4_ (D_ / 4)               // 128 float4 per emb row
#define TOUT_ (TK_ + TC_)          // 384
#define NEGINF_ (-1e20f)
#define INV_SQRT_D_ 0.044194173824159216f   // 1/sqrt(512)

// d_out layout (float): full_enc [N,384,512] | full_mask [N,384] | ck_attn [N,32]
#define OUT_MASK_OFF_ 1572864
#define OUT_ATTN_OFF_ 1575936

// ---------------------------------------------------------------
// Kernel 1 (136 blocks x 1024 thr):
//   blocks [0,8):    pool ctx row n -> ctx_use[n,:] (scaled); reset key/done.
//   blocks [8,136):  copy 16 context rows each into full_enc/full_mask.
__global__ __launch_bounds__(1024) void ctx_kernel(
        const int* __restrict__ src_tokens,
        const float* __restrict__ emb,
        float* __restrict__ ctx_use,
        float* __restrict__ full_enc,
        float* __restrict__ full_mask,
        unsigned long long* __restrict__ key,
        unsigned int* __restrict__ done_cnt) {
    const int bid = blockIdx.x;
    const int tid = threadIdx.x;
    const float4* emb4 = (const float4*)emb;

    if (bid >= N_) {
        // ---- ctx-copy block: 16 rows of the context region ----
        const int cb = bid - N_;               // 0..127
        const int lane = tid & 127;
        #pragma unroll
        for (int i = 0; i < 2; ++i) {
            const int g = cb * 16 + i * 8 + (tid >> 7);   // ctx row 0..2047
            const int n = g >> 8, t = g & 255;
            const int tok = src_tokens[n * TC_ + t];
            ((float4*)(full_enc + ((size_t)n * TOUT_ + TK_ + t) * D_))[lane] =
                emb4[(size_t)tok * D4_ + lane];
            if (lane == 0) full_mask[n * TOUT_ + TK_ + t] = (tok != 0) ? 1.0f : 0.0f;
        }
        return;
    }

    // ---- ctx pool: row n = bid ----
    __shared__ int s_tok[TC_];
    __shared__ float4 s_red[8][D4_];   // 16 KB
    __shared__ int s_cnt[8];
    if (tid == 0) { key[bid] = 0ull; done_cnt[bid] = 0u; }  // per-call reset
    if (tid < TC_) s_tok[tid] = src_tokens[bid * TC_ + tid];
    __syncthreads();

    const int tg = tid >> 7, lane = tid & 127;
    float4 acc = make_float4(0.f, 0.f, 0.f, 0.f);
    int cnt = 0;
    #pragma unroll 8
    for (int t = tg; t < TC_; t += 8) {
        const int tok = s_tok[t];
        if (tok != 0) {
            ++cnt;
            const float4 v = emb4[(size_t)tok * D4_ + lane];
            acc.x += v.x; acc.y += v.y; acc.z += v.z; acc.w += v.w;
        }
    }
    s_red[tg][lane] = acc;
    if (lane == 0) s_cnt[tg] = cnt;
    __syncthreads();

    if (tg == 0) {
        float4 tot = s_red[0][lane];
        #pragma unroll
        for (int j = 1; j < 8; ++j) {
            const float4 v = s_red[j][lane];
            tot.x += v.x; tot.y += v.y; tot.z += v.z; tot.w += v.w;
        }
        int c = 0;
        #pragma unroll
        for (int j = 0; j < 8; ++j) c += s_cnt[j];
        const float sc = INV_SQRT_D_ / sqrtf((float)c);
        tot.x *= sc; tot.y *= sc; tot.z *= sc; tot.w *= sc;
        ((float4*)(ctx_use + (size_t)bid * D_))[lane] = tot;
    }
}

// ---------------------------------------------------------------
// Kernel 2 (256 blocks x 1024 thr): block (n,k) computes
//   ck_attn[n,k] = sum_t 1[tok!=0] * emb[tok] . ctx_use[n]  * inv_sqrt_d/sqrt(cnt)
// (know_use never materialized), then masked value -> packed atomicMax argmax.
// The LAST block of each row n (done-counter) gathers the chosen sentence rows.
__global__ __launch_bounds__(1024) void know_kernel(
        const int* __restrict__ know_tokens,
        const int* __restrict__ ck_mask,
        const int* __restrict__ cs_ids,
        const int* __restrict__ use_cs_ids,
        const float* __restrict__ emb,
        const float* __restrict__ ctx_use,
        float* __restrict__ ck_attn,
        float* __restrict__ full_enc,
        float* __restrict__ full_mask,
        unsigned long long* __restrict__ key,
        unsigned int* __restrict__ done_cnt) {
    const int bid = blockIdx.x;
    const int tid = threadIdx.x;
    const int n = bid >> 5, k = bid & 31;
    const float4* emb4 = (const float4*)emb;

    __shared__ int s_tok[TK_];
    __shared__ float s_part[16];
    __shared__ int s_bcnt[2];
    __shared__ int s_chosen;

    if (tid < TK_) {
        const int tok = know_tokens[(size_t)bid * TK_ + tid];
        s_tok[tid] = tok;
        const unsigned long long b = __ballot(tok != 0);   // waves 0,1 fully active
        if ((tid & 63) == 0) s_bcnt[tid >> 6] = (int)__popcll(b);
    }
    __syncthreads();

    const int tg = tid >> 7, lane = tid & 127;   // 8 token-groups x 128 dim-lanes
    const float4 c = ((const float4*)(ctx_use + (size_t)n * D_))[lane];
    float acc = 0.f;
    #pragma unroll 8
    for (int t = tg; t < TK_; t += 8) {
        const int tok = s_tok[t];
        if (tok != 0) {
            const float4 v = emb4[(size_t)tok * D4_ + lane];
            acc += v.x * c.x + v.y * c.y + v.z * c.z + v.w * c.w;
        }
    }
    #pragma unroll
    for (int off = 32; off > 0; off >>= 1) acc += __shfl_down(acc, off, 64);
    if ((tid & 63) == 0) s_part[tid >> 6] = acc;
    __syncthreads();

    if (tid == 0) {
        float v = 0.f;
        #pragma unroll
        for (int j = 0; j < 16; ++j) v += s_part[j];
        const int cnt = s_bcnt[0] + s_bcnt[1];
        v *= INV_SQRT_D_ / sqrtf((float)cnt);
        if (ck_mask[n * K_ + k] == 0) v = NEGINF_;
        ck_attn[n * K_ + k] = v;

        // order-preserving float encoding; ties -> smaller k (numpy first-max)
        unsigned ub = __float_as_uint(v);
        ub = (ub & 0x80000000u) ? ~ub : (ub | 0x80000000u);
        const unsigned long long pk =
            ((unsigned long long)ub << 32) | (unsigned)(K_ - 1 - k);
        atomicMax(&key[n], pk);
        __threadfence();
        const unsigned old = atomicAdd(&done_cnt[n], 1u);
        int ch = -1;
        if (old == (unsigned)(K_ - 1)) {             // last block of row n
            __threadfence();
            const unsigned long long kk = atomicMax(&key[n], 0ull);  // atomic read
            const int kbest = (K_ - 1) - (int)(kk & 0xffffffffull);
            ch = (use_cs_ids[0] != 0) ? cs_ids[n] : kbest;
        }
        s_chosen = ch;
    }
    __syncthreads();

    const int ch = s_chosen;
    if (ch >= 0) {
        // epilogue: gather chosen knowledge sentence (128 rows) -> full_enc/full_mask
        const int* crow = know_tokens + ((size_t)n * K_ + ch) * TK_;
        #pragma unroll 4
        for (int r = tg; r < TK_; r += 8) {
            const int tok = crow[r];
            ((float4*)(full_enc + ((size_t)n * TOUT_ + r) * D_))[lane] =
                emb4[(size_t)tok * D4_ + lane];
            if (lane == 0) full_mask[n * TOUT_ + r] = (tok != 0) ? 1.0f : 0.0f;
        }
    }
}

// ---------------------------------------------------------------
extern "C" void kernel_launch(void* const* d_in, const int* in_sizes, int n_in,
                              void* d_out, int out_size, void* d_ws, size_t ws_size,
                              hipStream_t stream) {
    const int*   src_tokens  = (const int*)d_in[0];   // [N,Tc]
    const int*   know_tokens = (const int*)d_in[1];   // [N,K,Tk]
    const int*   ck_mask     = (const int*)d_in[2];   // [N,K] 0/1
    const int*   cs_ids      = (const int*)d_in[3];   // [N]
    const int*   use_cs_ids  = (const int*)d_in[4];   // scalar
    const float* emb         = (const float*)d_in[5]; // [V,D]

    float* out = (float*)d_out;
    float* full_enc  = out;
    float* full_mask = out + OUT_MASK_OFF_;
    float* ck_attn   = out + OUT_ATTN_OFF_;

    // workspace: key[8] ULL | done[8] uint | ctx_use[8*512] float
    char* ws = (char*)d_ws;
    unsigned long long* key = (unsigned long long*)ws;          // 64 B
    unsigned int* done_cnt  = (unsigned int*)(ws + 64);         // 32 B
    float* ctx_use          = (float*)(ws + 128);               // 16 KB

    ctx_kernel<<<N_ + 128, 1024, 0, stream>>>(src_tokens, emb, ctx_use,
                                              full_enc, full_mask, key, done_cnt);
    know_kernel<<<N_ * K_, 1024, 0, stream>>>(know_tokens, ck_mask, cs_ids,
                                              use_cs_ids, emb, ctx_use, ck_attn,
                                              full_enc, full_mask, key, done_cnt);
}

// Round 5
// 27.129 us; speedup vs baseline: 1.6223x; 1.6223x over previous
//
#include <hip/hip_runtime.h>

// Problem constants (from reference setup_inputs)
#define N_  8
#define K_  32
#define TK_ 128
#define TC_ 256
#define D_  512
#define D4_ (D_ / 4)               // 128 float4 per emb row
#define TOUT_ (TK_ + TC_)          // 384
#define NEGINF_ (-1e20f)
#define INV_SQRT_D_ 0.044194173824159216f   // 1/sqrt(512)

// d_out layout (float): full_enc [N,384,512] | full_mask [N,384] | ck_attn [N,32]
#define OUT_MASK_OFF_ 1572864
#define OUT_ATTN_OFF_ 1575936

#define QPC_ 4                      // ctx quarters per row
#define QTOK_ (TC_ / QPC_)          // 64 tokens per quarter

// ---------------------------------------------------------------
// Kernel 1 (32 blocks x 1024): block (n,q) pools ctx tokens [q*64,(q+1)*64)
// into partial[(n*4+q)][512] (+count). q==0 block also resets key[n].
__global__ __launch_bounds__(1024) void ctx_pool_kernel(
        const int* __restrict__ src_tokens,
        const float* __restrict__ emb,
        float4* __restrict__ partial,        // [32][128] float4
        int* __restrict__ pcnt,              // [32]
        unsigned long long* __restrict__ key) {
    const int bid = blockIdx.x;
    const int n = bid >> 2, q = bid & 3;
    const int tid = threadIdx.x;
    const float4* emb4 = (const float4*)emb;

    __shared__ int s_tok[QTOK_];
    __shared__ float4 s_red[8][D4_];   // 16 KB
    __shared__ int s_cnt[8];

    if (tid == 0 && q == 0) key[n] = 0ull;   // per-call reset (before K2)
    if (tid < QTOK_) s_tok[tid] = src_tokens[n * TC_ + q * QTOK_ + tid];
    __syncthreads();

    const int tg = tid >> 7, lane = tid & 127;
    float4 acc = make_float4(0.f, 0.f, 0.f, 0.f);
    int cnt = 0;
    #pragma unroll 8
    for (int t = tg; t < QTOK_; t += 8) {
        const int tok = s_tok[t];
        if (tok != 0) {
            ++cnt;
            const float4 v = emb4[(size_t)tok * D4_ + lane];
            acc.x += v.x; acc.y += v.y; acc.z += v.z; acc.w += v.w;
        }
    }
    s_red[tg][lane] = acc;
    if (lane == 0) s_cnt[tg] = cnt;
    __syncthreads();

    if (tg == 0) {
        float4 tot = s_red[0][lane];
        #pragma unroll
        for (int j = 1; j < 8; ++j) {
            const float4 v = s_red[j][lane];
            tot.x += v.x; tot.y += v.y; tot.z += v.z; tot.w += v.w;
        }
        partial[bid * D4_ + lane] = tot;
        if (lane == 0) {
            int c = 0;
            #pragma unroll
            for (int j = 0; j < 8; ++j) c += s_cnt[j];
            pcnt[bid] = c;
        }
    }
}

// ---------------------------------------------------------------
// Kernel 2 (384 blocks x 1024):
//  blocks [0,256): fused know pool+dot for (n,k): combine ctx partials,
//    gather emb rows, dot, scale, mask -> ck_attn + packed atomicMax key[n].
//  blocks [256,384): copy 16 context rows each into full_enc/full_mask.
__global__ __launch_bounds__(1024) void know_kernel(
        const int* __restrict__ src_tokens,
        const int* __restrict__ know_tokens,
        const int* __restrict__ ck_mask,
        const float* __restrict__ emb,
        const float4* __restrict__ partial,
        const int* __restrict__ pcnt,
        float* __restrict__ ck_attn,
        float* __restrict__ full_enc,
        float* __restrict__ full_mask,
        unsigned long long* __restrict__ key) {
    const int bid = blockIdx.x;
    const int tid = threadIdx.x;
    const float4* emb4 = (const float4*)emb;

    if (bid >= N_ * K_) {
        // ---- ctx-copy block: 16 rows of the context region ----
        const int cb = bid - N_ * K_;          // 0..127
        const int lane = tid & 127;
        #pragma unroll
        for (int i = 0; i < 2; ++i) {
            const int g = cb * 16 + i * 8 + (tid >> 7);   // ctx row 0..2047
            const int n = g >> 8, t = g & 255;
            const int tok = src_tokens[n * TC_ + t];
            ((float4*)(full_enc + ((size_t)n * TOUT_ + TK_ + t) * D_))[lane] =
                emb4[(size_t)tok * D4_ + lane];
            if (lane == 0) full_mask[n * TOUT_ + TK_ + t] = (tok != 0) ? 1.0f : 0.0f;
        }
        return;
    }

    const int n = bid >> 5, k = bid & 31;

    __shared__ float4 s_ctx[D4_];    // scaled ctx_use row (2 KB)
    __shared__ int s_tok[TK_];
    __shared__ float s_part[16];
    __shared__ int s_bcnt[2];

    if (tid < D4_) {
        // combine the 4 ctx partials -> scaled ctx_use slice
        float4 c = partial[(n * QPC_ + 0) * D4_ + tid];
        int cc = pcnt[n * QPC_ + 0];
        #pragma unroll
        for (int qq = 1; qq < QPC_; ++qq) {
            const float4 v = partial[(n * QPC_ + qq) * D4_ + tid];
            c.x += v.x; c.y += v.y; c.z += v.z; c.w += v.w;
            cc += pcnt[n * QPC_ + qq];
        }
        const float sc = INV_SQRT_D_ / sqrtf((float)cc);
        c.x *= sc; c.y *= sc; c.z *= sc; c.w *= sc;
        s_ctx[tid] = c;

        const int tok = know_tokens[(size_t)bid * TK_ + tid];
        s_tok[tid] = tok;
        const unsigned long long b = __ballot(tok != 0);   // waves 0,1 fully active
        if ((tid & 63) == 0) s_bcnt[tid >> 6] = (int)__popcll(b);
    }
    __syncthreads();

    const int tg = tid >> 7, lane = tid & 127;   // 8 token-groups x 128 dim-lanes
    const float4 c = s_ctx[lane];
    float acc = 0.f;
    #pragma unroll 8
    for (int t = tg; t < TK_; t += 8) {
        const int tok = s_tok[t];
        if (tok != 0) {
            const float4 v = emb4[(size_t)tok * D4_ + lane];
            acc += v.x * c.x + v.y * c.y + v.z * c.z + v.w * c.w;
        }
    }
    #pragma unroll
    for (int off = 32; off > 0; off >>= 1) acc += __shfl_down(acc, off, 64);
    if ((tid & 63) == 0) s_part[tid >> 6] = acc;
    __syncthreads();

    if (tid == 0) {
        float v = 0.f;
        #pragma unroll
        for (int j = 0; j < 16; ++j) v += s_part[j];
        const int cnt = s_bcnt[0] + s_bcnt[1];
        v *= INV_SQRT_D_ / sqrtf((float)cnt);
        if (ck_mask[n * K_ + k] == 0) v = NEGINF_;
        ck_attn[n * K_ + k] = v;

        // order-preserving float encoding; ties -> smaller k (numpy first-max)
        unsigned ub = __float_as_uint(v);
        ub = (ub & 0x80000000u) ? ~ub : (ub | 0x80000000u);
        const unsigned long long pk =
            ((unsigned long long)ub << 32) | (unsigned)(K_ - 1 - k);
        atomicMax(&key[n], pk);
    }
}

// ---------------------------------------------------------------
// Kernel 3 (1024 blocks x 128): chosen-knowledge gather.
// Each block: derive chosen from key[n] (finalized in K2), copy one row.
__global__ void gather_cs_kernel(const int* __restrict__ know_tokens,
                                 const int* __restrict__ cs_ids,
                                 const int* __restrict__ use_cs_ids,
                                 const unsigned long long* __restrict__ key,
                                 const float* __restrict__ emb,
                                 float* __restrict__ full_enc,
                                 float* __restrict__ full_mask) {
    const int bid = blockIdx.x;
    const int n = bid >> 7;
    const int r = bid & 127;
    const int tid = threadIdx.x;

    const int kbest = (K_ - 1) - (int)(key[n] & 0xffffffffull);
    const int ch = (use_cs_ids[0] != 0) ? cs_ids[n] : kbest;

    const int token = know_tokens[((size_t)n * K_ + ch) * TK_ + r];
    ((float4*)(full_enc + ((size_t)n * TOUT_ + r) * D_))[tid] =
        ((const float4*)(emb + (size_t)token * D_))[tid];
    if (tid == 0) full_mask[n * TOUT_ + r] = (token != 0) ? 1.0f : 0.0f;
}

// ---------------------------------------------------------------
extern "C" void kernel_launch(void* const* d_in, const int* in_sizes, int n_in,
                              void* d_out, int out_size, void* d_ws, size_t ws_size,
                              hipStream_t stream) {
    const int*   src_tokens  = (const int*)d_in[0];   // [N,Tc]
    const int*   know_tokens = (const int*)d_in[1];   // [N,K,Tk]
    const int*   ck_mask     = (const int*)d_in[2];   // [N,K] 0/1
    const int*   cs_ids      = (const int*)d_in[3];   // [N]
    const int*   use_cs_ids  = (const int*)d_in[4];   // scalar
    const float* emb         = (const float*)d_in[5]; // [V,D]

    float* out = (float*)d_out;
    float* full_enc  = out;
    float* full_mask = out + OUT_MASK_OFF_;
    float* ck_attn   = out + OUT_ATTN_OFF_;

    // workspace: key[8] ULL | pcnt[32] int | partial[32*128] float4
    char* ws = (char*)d_ws;
    unsigned long long* key = (unsigned long long*)ws;      // 64 B
    int* pcnt       = (int*)(ws + 64);                      // 128 B
    float4* partial = (float4*)(ws + 256);                  // 64 KB

    ctx_pool_kernel<<<N_ * QPC_, 1024, 0, stream>>>(src_tokens, emb,
                                                    partial, pcnt, key);
    know_kernel<<<N_ * K_ + 128, 1024, 0, stream>>>(src_tokens, know_tokens,
                                                    ck_mask, emb, partial, pcnt,
                                                    ck_attn, full_enc, full_mask, key);
    gather_cs_kernel<<<N_ * TK_, 128, 0, stream>>>(know_tokens, cs_ids, use_cs_ids,
                                                   key, emb, full_enc, full_mask);
}